// Round 1
// baseline (1602.171 us; speedup 1.0000x reference)
//
#include <hip/hip_runtime.h>

#define NN 100000
#define NE 1600000
#define DIN 32
#define DLAT 64
#define KHOPS 3
#define NLAYERS 5

// ---------------- setup kernels ----------------

__global__ void deg_cnt_kernel(const int* __restrict__ col, const float* __restrict__ w,
                               float* __restrict__ deg, unsigned* __restrict__ cnt, int E) {
    int e = blockIdx.x * blockDim.x + threadIdx.x;
    if (e < E) {
        int c = col[e];
        atomicAdd(&deg[c], w[e]);
        atomicAdd(&cnt[c], 1u);
    }
}

__global__ void dinv_kernel(float* __restrict__ deg, int n) {
    int i = blockIdx.x * blockDim.x + threadIdx.x;
    if (i < n) {
        float d = deg[i];
        deg[i] = d > 0.f ? rsqrtf(d) : 0.f;
    }
}

// exclusive scan of cnt[] (N elems) -> offsets[], 1024 elems per block
__global__ void scan_phase1(const unsigned* __restrict__ cnt, unsigned* __restrict__ bsum, int n) {
    __shared__ unsigned sh[256];
    int t = threadIdx.x;
    int base = blockIdx.x * 1024 + t * 4;
    unsigned s = 0;
#pragma unroll
    for (int j = 0; j < 4; j++) { int i = base + j; if (i < n) s += cnt[i]; }
    sh[t] = s; __syncthreads();
    for (int d = 128; d > 0; d >>= 1) {
        if (t < d) sh[t] += sh[t + d];
        __syncthreads();
    }
    if (t == 0) bsum[blockIdx.x] = sh[0];
}

__global__ void scan_phase2(const unsigned* __restrict__ bsum, unsigned* __restrict__ bbase, int nb) {
    __shared__ unsigned sh[128];
    int t = threadIdx.x;
    unsigned v = (t < nb) ? bsum[t] : 0u;
    sh[t] = v; __syncthreads();
    for (int d = 1; d < 128; d <<= 1) {
        unsigned u = (t >= d) ? sh[t - d] : 0u;
        __syncthreads();
        sh[t] += u;
        __syncthreads();
    }
    if (t < nb) bbase[t] = sh[t] - v;   // exclusive
}

__global__ void scan_phase3(const unsigned* __restrict__ cnt, const unsigned* __restrict__ bbase,
                            unsigned* __restrict__ offsets, int n) {
    __shared__ unsigned sh[256];
    int t = threadIdx.x;
    int base = blockIdx.x * 1024 + t * 4;
    unsigned c[4]; unsigned s = 0;
#pragma unroll
    for (int j = 0; j < 4; j++) { int i = base + j; c[j] = (i < n) ? cnt[i] : 0u; s += c[j]; }
    sh[t] = s; __syncthreads();
    for (int d = 1; d < 256; d <<= 1) {
        unsigned u = (t >= d) ? sh[t - d] : 0u;
        __syncthreads();
        sh[t] += u;
        __syncthreads();
    }
    unsigned o = bbase[blockIdx.x] + sh[t] - s;  // exclusive base for this thread
#pragma unroll
    for (int j = 0; j < 4; j++) {
        int i = base + j;
        if (i < n) { offsets[i] = o; o += c[j]; }
    }
}

__global__ void csr_build(const int* __restrict__ row, const int* __restrict__ col,
                          const float* __restrict__ w, const float* __restrict__ dinv,
                          const unsigned* __restrict__ offsets, unsigned* __restrict__ cursor,
                          int* __restrict__ csr_row, float* __restrict__ csr_norm, int E) {
    int e = blockIdx.x * blockDim.x + threadIdx.x;
    if (e < E) {
        int r = row[e], c = col[e];
        unsigned p = offsets[c] + atomicAdd(&cursor[c], 1u);
        csr_row[p] = r;
        csr_norm[p] = dinv[r] * w[e] * dinv[c];
    }
}

// ---------------- SpMM: dst[c][:] = sum_e norm[e] * h[row[e]][:] ----------------

template <int DIM>
__global__ __launch_bounds__(256) void spmm_kernel(const float* __restrict__ h, float* __restrict__ dst,
                            const int* __restrict__ csr_row, const float* __restrict__ csr_norm,
                            const unsigned* __restrict__ offsets, const unsigned* __restrict__ cnt,
                            int n) {
    constexpr int TPN = DIM / 4;          // threads per node
    constexpr int NPB = 256 / TPN;        // nodes per block
    int node = blockIdx.x * NPB + threadIdx.x / TPN;
    int f = (threadIdx.x % TPN) * 4;
    if (node >= n) return;
    unsigned off = offsets[node];
    unsigned c = cnt[node];
    float4 acc = {0.f, 0.f, 0.f, 0.f};
    for (unsigned e = off; e < off + c; ++e) {
        int r = csr_row[e];
        float w = csr_norm[e];
        float4 v = *reinterpret_cast<const float4*>(h + (size_t)r * DIM + f);
        acc.x += w * v.x; acc.y += w * v.y; acc.z += w * v.z; acc.w += w * v.w;
    }
    *reinterpret_cast<float4*>(dst + (size_t)node * DIM + f) = acc;
}

// ---------------- dense: C (+)= A @ W  [+bias, relu -> dst] ----------------
// A: n x IN, W: IN x 64, C: n x 64

template <int IN, bool INIT, bool FINAL>
__global__ __launch_bounds__(256) void matmul_kernel(const float* __restrict__ A, const float* __restrict__ W,
                              float* __restrict__ C, const float* __restrict__ bias,
                              float* __restrict__ dst, int n) {
    constexpr int AT_S = IN + 12;  // padded LDS stride (words): keeps 16B align + bank spread
    __shared__ float Wl[IN * 64];
    __shared__ float At[64 * AT_S];
    int t = threadIdx.x;
    int nodeBase = blockIdx.x * 64;

#pragma unroll
    for (int idx = t * 4; idx < IN * 64; idx += 1024)
        *reinterpret_cast<float4*>(&Wl[idx]) = *reinterpret_cast<const float4*>(&W[idx]);

#pragma unroll
    for (int idx = t * 4; idx < 64 * IN; idx += 1024) {
        int nd = idx / IN, i = idx % IN;
        float4 v = {0.f, 0.f, 0.f, 0.f};
        if (nodeBase + nd < n)
            v = *reinterpret_cast<const float4*>(&A[(size_t)(nodeBase + nd) * IN + i]);
        *reinterpret_cast<float4*>(&At[nd * AT_S + i]) = v;
    }
    __syncthreads();

    int tx = t % 16;   // output quad j = tx*4..
    int ty = t / 16;   // node group: nodes ty*4 .. ty*4+3
    float4 acc[4] = {};
    for (int i4 = 0; i4 < IN; i4 += 4) {
        float4 av[4];
#pragma unroll
        for (int nn = 0; nn < 4; ++nn)
            av[nn] = *reinterpret_cast<const float4*>(&At[(ty * 4 + nn) * AT_S + i4]);
#pragma unroll
        for (int j = 0; j < 4; ++j) {
            float4 wv = *reinterpret_cast<const float4*>(&Wl[(i4 + j) * 64 + tx * 4]);
#pragma unroll
            for (int nn = 0; nn < 4; ++nn) {
                float a = reinterpret_cast<const float*>(&av[nn])[j];
                acc[nn].x += a * wv.x; acc[nn].y += a * wv.y;
                acc[nn].z += a * wv.z; acc[nn].w += a * wv.w;
            }
        }
    }

    float4 bv = {0.f, 0.f, 0.f, 0.f};
    if (FINAL) bv = *reinterpret_cast<const float4*>(&bias[tx * 4]);
#pragma unroll
    for (int nn = 0; nn < 4; ++nn) {
        int node = nodeBase + ty * 4 + nn;
        if (node >= n) continue;
        size_t o = (size_t)node * 64 + tx * 4;
        float4 r = acc[nn];
        if (!INIT) {
            float4 cv = *reinterpret_cast<const float4*>(&C[o]);
            r.x += cv.x; r.y += cv.y; r.z += cv.z; r.w += cv.w;
        }
        if (FINAL) {
            r.x = fmaxf(r.x + bv.x, 0.f);
            r.y = fmaxf(r.y + bv.y, 0.f);
            r.z = fmaxf(r.z + bv.z, 0.f);
            r.w = fmaxf(r.w + bv.w, 0.f);
            *reinterpret_cast<float4*>(&dst[o]) = r;
        } else {
            *reinterpret_cast<float4*>(&C[o]) = r;
        }
    }
}

// ---------------- host ----------------

extern "C" void kernel_launch(void* const* d_in, const int* in_sizes, int n_in,
                              void* d_out, int out_size, void* d_ws, size_t ws_size,
                              hipStream_t stream) {
    const float* x  = (const float*)d_in[0];
    const int*   ei = (const int*)d_in[1];
    const float* ew = (const float*)d_in[2];
    const float* W0 = (const float*)d_in[3];
    const float* b0 = (const float*)d_in[4];
    const float* Ws = (const float*)d_in[5];
    const float* bs = (const float*)d_in[6];
    float* out = (float*)d_out;

    const int* row = ei;
    const int* col = ei + NE;

    char* wsp = (char*)d_ws;
    auto alloc = [&](size_t bytes) -> char* {
        char* p = wsp;
        wsp += (bytes + 255) & ~(size_t)255;
        return p;
    };
    float*    deg     = (float*)alloc(NN * 4);        // becomes dinv in-place
    unsigned* cnt     = (unsigned*)alloc(NN * 4);
    unsigned* cursor  = (unsigned*)alloc(NN * 4);
    unsigned* offsets = (unsigned*)alloc(NN * 4);
    unsigned* bsum    = (unsigned*)alloc(256 * 4);
    unsigned* bbase   = (unsigned*)alloc(256 * 4);
    int*      csr_row = (int*)alloc((size_t)NE * 4);
    float*    csr_nrm = (float*)alloc((size_t)NE * 4);
    float*    P0      = (float*)alloc((size_t)NN * 64 * 4);
    float*    P1      = (float*)alloc((size_t)NN * 64 * 4);

    hipMemsetAsync(deg, 0, NN * 4, stream);
    hipMemsetAsync(cnt, 0, NN * 4, stream);
    hipMemsetAsync(cursor, 0, NN * 4, stream);

    const int EB = NE / 256;                 // 6250
    deg_cnt_kernel<<<EB, 256, 0, stream>>>(col, ew, deg, cnt, NE);
    dinv_kernel<<<(NN + 255) / 256, 256, 0, stream>>>(deg, NN);
    const int NB = (NN + 1023) / 1024;       // 98
    scan_phase1<<<NB, 256, 0, stream>>>(cnt, bsum, NN);
    scan_phase2<<<1, 128, 0, stream>>>(bsum, bbase, NB);
    scan_phase3<<<NB, 256, 0, stream>>>(cnt, bbase, offsets, NN);
    csr_build<<<EB, 256, 0, stream>>>(row, col, ew, deg, offsets, cursor, csr_row, csr_nrm, NE);

    const int MMB   = (NN + 63) / 64;        // 1563
    const int SP32B = (NN + 31) / 32;        // 3125
    const int SP64B = (NN + 15) / 16;        // 6250

    // ---- layer 0 (IN=32) ----
    // out = x@W0[0]
    matmul_kernel<32, true, false><<<MMB, 256, 0, stream>>>(x, W0, out, nullptr, nullptr, NN);
    // h1 = S(x)
    spmm_kernel<32><<<SP32B, 256, 0, stream>>>(x, P1, csr_row, csr_nrm, offsets, cnt, NN);
    matmul_kernel<32, false, false><<<MMB, 256, 0, stream>>>(P1, W0 + 2048, out, nullptr, nullptr, NN);
    spmm_kernel<32><<<SP32B, 256, 0, stream>>>(P1, P0, csr_row, csr_nrm, offsets, cnt, NN);
    matmul_kernel<32, false, false><<<MMB, 256, 0, stream>>>(P0, W0 + 4096, out, nullptr, nullptr, NN);
    spmm_kernel<32><<<SP32B, 256, 0, stream>>>(P0, P1, csr_row, csr_nrm, offsets, cnt, NN);
    // out = relu(out + h3@W0[3] + b0) -> P0 (next layer input)
    matmul_kernel<32, false, true><<<MMB, 256, 0, stream>>>(P1, W0 + 6144, out, b0, P0, NN);

    // ---- layers 1..4 (IN=64) ----
    for (int l = 0; l < NLAYERS - 1; ++l) {
        const float* Wl = Ws + (size_t)l * 4 * 64 * 64;
        const float* bl = bs + (size_t)l * 64;
        float* dstF = (l == NLAYERS - 2) ? out : P0;
        matmul_kernel<64, true, false><<<MMB, 256, 0, stream>>>(P0, Wl, out, nullptr, nullptr, NN);
        spmm_kernel<64><<<SP64B, 256, 0, stream>>>(P0, P1, csr_row, csr_nrm, offsets, cnt, NN);
        matmul_kernel<64, false, false><<<MMB, 256, 0, stream>>>(P1, Wl + 4096, out, nullptr, nullptr, NN);
        spmm_kernel<64><<<SP64B, 256, 0, stream>>>(P1, P0, csr_row, csr_nrm, offsets, cnt, NN);
        matmul_kernel<64, false, false><<<MMB, 256, 0, stream>>>(P0, Wl + 8192, out, nullptr, nullptr, NN);
        spmm_kernel<64><<<SP64B, 256, 0, stream>>>(P0, P1, csr_row, csr_nrm, offsets, cnt, NN);
        matmul_kernel<64, false, true><<<MMB, 256, 0, stream>>>(P1, Wl + 12288, out, bl, dstF, NN);
    }
}

// Round 3
// 1150.498 us; speedup vs baseline: 1.3926x; 1.3926x over previous
//
#include <hip/hip_runtime.h>
#include <hip/hip_fp16.h>

#define NN 100000
#define NE 1600000

typedef __half half_t;

// ---------------- helpers ----------------

__device__ inline float4 load4(const float* p) {
    return *reinterpret_cast<const float4*>(p);
}
__device__ inline float4 load4(const half_t* p) {
    uint2 u = *reinterpret_cast<const uint2*>(p);
    __half2 a = *reinterpret_cast<__half2*>(&u.x);
    __half2 b = *reinterpret_cast<__half2*>(&u.y);
    float2 fa = __half22float2(a), fb = __half22float2(b);
    return make_float4(fa.x, fa.y, fb.x, fb.y);
}
__device__ inline void store_half4(half_t* p, float4 v) {
    __half2 a = __floats2half2_rn(v.x, v.y);
    __half2 b = __floats2half2_rn(v.z, v.w);
    uint2 u;
    u.x = *reinterpret_cast<unsigned*>(&a);
    u.y = *reinterpret_cast<unsigned*>(&b);
    *reinterpret_cast<uint2*>(p) = u;
}

// ---------------- setup kernels ----------------

__global__ void cnt_hist(const int* __restrict__ col, unsigned* __restrict__ cnt, int E) {
    int e = blockIdx.x * blockDim.x + threadIdx.x;
    if (e < E) atomicAdd(&cnt[col[e]], 1u);
}

__global__ void scan_phase1(const unsigned* __restrict__ cnt, unsigned* __restrict__ bsum, int n) {
    __shared__ unsigned sh[256];
    int t = threadIdx.x;
    int base = blockIdx.x * 1024 + t * 4;
    unsigned s = 0;
#pragma unroll
    for (int j = 0; j < 4; j++) { int i = base + j; if (i < n) s += cnt[i]; }
    sh[t] = s; __syncthreads();
    for (int d = 128; d > 0; d >>= 1) {
        if (t < d) sh[t] += sh[t + d];
        __syncthreads();
    }
    if (t == 0) bsum[blockIdx.x] = sh[0];
}

__global__ void scan_phase2(const unsigned* __restrict__ bsum, unsigned* __restrict__ bbase, int nb) {
    __shared__ unsigned sh[128];
    int t = threadIdx.x;
    unsigned v = (t < nb) ? bsum[t] : 0u;
    sh[t] = v; __syncthreads();
    for (int d = 1; d < 128; d <<= 1) {
        unsigned u = (t >= d) ? sh[t - d] : 0u;
        __syncthreads();
        sh[t] += u;
        __syncthreads();
    }
    if (t < nb) bbase[t] = sh[t] - v;   // exclusive
}

__global__ void scan_phase3(const unsigned* __restrict__ cnt, const unsigned* __restrict__ bbase,
                            unsigned* __restrict__ offsets, int n) {
    __shared__ unsigned sh[256];
    int t = threadIdx.x;
    int base = blockIdx.x * 1024 + t * 4;
    unsigned c[4]; unsigned s = 0;
#pragma unroll
    for (int j = 0; j < 4; j++) { int i = base + j; c[j] = (i < n) ? cnt[i] : 0u; s += c[j]; }
    sh[t] = s; __syncthreads();
    for (int d = 1; d < 256; d <<= 1) {
        unsigned u = (t >= d) ? sh[t - d] : 0u;
        __syncthreads();
        sh[t] += u;
        __syncthreads();
    }
    unsigned o = bbase[blockIdx.x] + sh[t] - s;
#pragma unroll
    for (int j = 0; j < 4; j++) {
        int i = base + j;
        if (i < n) { offsets[i] = o; o += c[j]; }
    }
}

__global__ void csr_build(const int* __restrict__ row, const int* __restrict__ col,
                          const float* __restrict__ w, const unsigned* __restrict__ offsets,
                          unsigned* __restrict__ cursor, int2* __restrict__ ent, int E) {
    int e = blockIdx.x * blockDim.x + threadIdx.x;
    if (e < E) {
        int c = col[e];
        unsigned p = offsets[c] + atomicAdd(&cursor[c], 1u);
        ent[p] = make_int2(row[e], __float_as_int(w[e]));
    }
}

// deg[i] = sum of w over CSR segment i (sequential, no atomics); dinv = rsqrt
__global__ void deg_dinv(const int2* __restrict__ ent, const unsigned* __restrict__ offs,
                         const unsigned* __restrict__ cnt, float* __restrict__ dinv, int n) {
    int i = blockIdx.x * blockDim.x + threadIdx.x;
    if (i < n) {
        unsigned o = offs[i], c = cnt[i];
        float s = 0.f;
        for (unsigned k = 0; k < c; ++k) s += __int_as_float(ent[o + k].y);
        dinv[i] = s > 0.f ? rsqrtf(s) : 0.f;
    }
}

// ent.y = dinv[row] * w   (dst-side dinv applied in spmm epilogue)
__global__ void norm_scale(int2* __restrict__ ent, const float* __restrict__ dinv, int E) {
    int e = blockIdx.x * blockDim.x + threadIdx.x;
    if (e < E) {
        int2 v = ent[e];
        v.y = __float_as_int(dinv[v.x] * __int_as_float(v.y));
        ent[e] = v;
    }
}

// ---------------- dense: C = A @ W (k=0 hop) ----------------

template <int IN, typename AT>
__global__ __launch_bounds__(256) void matmul_kernel(const AT* __restrict__ A, const float* __restrict__ W,
                                                     float* __restrict__ C, int n) {
    constexpr int AT_S = IN + 12;
    __shared__ float Wl[IN * 64];
    __shared__ float At[64 * AT_S];
    int t = threadIdx.x;
    int nodeBase = blockIdx.x * 64;

#pragma unroll
    for (int idx = t * 4; idx < IN * 64; idx += 1024)
        *reinterpret_cast<float4*>(&Wl[idx]) = *reinterpret_cast<const float4*>(&W[idx]);

#pragma unroll
    for (int idx = t * 4; idx < 64 * IN; idx += 1024) {
        int nd = idx / IN, i = idx % IN;
        float4 v = {0.f, 0.f, 0.f, 0.f};
        if (nodeBase + nd < n) v = load4(A + (size_t)(nodeBase + nd) * IN + i);
        *reinterpret_cast<float4*>(&At[nd * AT_S + i]) = v;
    }
    __syncthreads();

    int tx = t % 16;
    int ty = t / 16;
    float4 acc[4] = {};
    for (int i4 = 0; i4 < IN; i4 += 4) {
        float4 av[4];
#pragma unroll
        for (int nn = 0; nn < 4; ++nn)
            av[nn] = *reinterpret_cast<const float4*>(&At[(ty * 4 + nn) * AT_S + i4]);
#pragma unroll
        for (int j = 0; j < 4; ++j) {
            float4 wv = *reinterpret_cast<const float4*>(&Wl[(i4 + j) * 64 + tx * 4]);
#pragma unroll
            for (int nn = 0; nn < 4; ++nn) {
                float a = reinterpret_cast<const float*>(&av[nn])[j];
                acc[nn].x += a * wv.x; acc[nn].y += a * wv.y;
                acc[nn].z += a * wv.z; acc[nn].w += a * wv.w;
            }
        }
    }
#pragma unroll
    for (int nn = 0; nn < 4; ++nn) {
        int node = nodeBase + ty * 4 + nn;
        if (node >= n) continue;
        *reinterpret_cast<float4*>(&C[(size_t)node * 64 + tx * 4]) = acc[nn];
    }
}

// ---------------- fused SpMM + hop-matmul ----------------
// p[node] = dinv[node] * sum_e w_e * src[row_e]   (DIM wide)
// MODE 0: pout(f16) = p; acc += p @ W
// MODE 1: h(f16)   = relu(acc + p @ W + bias)
// MODE 2: out(f32) = relu(acc + p @ W + bias)

template <int DIM, typename SrcT, int MODE>
__global__ __launch_bounds__(256) void spmm_mm_kernel(
    const SrcT* __restrict__ src, half_t* __restrict__ pout,
    const int2* __restrict__ ent, const unsigned* __restrict__ offs,
    const unsigned* __restrict__ cnt, const float* __restrict__ dinv,
    const float* __restrict__ W, float* __restrict__ acc,
    const float* __restrict__ bias, half_t* __restrict__ hdst,
    float* __restrict__ fdst, int n)
{
    constexpr int TPN = DIM / 4;        // threads per node
    constexpr int NPB = 256 / TPN;      // nodes per block
    constexpr int PST = DIM + 4;        // padded LDS stride (words)
    constexpr int JP  = 256 / DIM;      // output columns per thread
    __shared__ float Wl[DIM * 64];
    __shared__ float ps[NPB * PST];
    int t = threadIdx.x;

#pragma unroll
    for (int idx = t * 4; idx < DIM * 64; idx += 1024)
        *reinterpret_cast<float4*>(&Wl[idx]) = *reinterpret_cast<const float4*>(&W[idx]);

    int ng   = t / TPN;
    int lane = t % TPN;
    int node = blockIdx.x * NPB + ng;
    bool valid = node < n;
    unsigned off = 0, c = 0; float dv = 0.f;
    if (valid) { off = offs[node]; c = cnt[node]; dv = dinv[node]; }
    const int f = lane * 4;

    float4 a = {0.f, 0.f, 0.f, 0.f};
#pragma unroll 2
    for (unsigned e = 0; e < c; ++e) {
        int2 en = ent[off + e];
        float w = __int_as_float(en.y);
        float4 v = load4(src + (size_t)en.x * DIM + f);
        a.x += w * v.x; a.y += w * v.y; a.z += w * v.z; a.w += w * v.w;
    }
    a.x *= dv; a.y *= dv; a.z *= dv; a.w *= dv;

    if (MODE == 0 && valid) store_half4(pout + (size_t)node * DIM + f, a);
    *reinterpret_cast<float4*>(&ps[ng * PST + f]) = a;
    __syncthreads();

    float4 m[JP / 4] = {};
    for (int i = 0; i < DIM; ++i) {
        float p = ps[ng * PST + i];
#pragma unroll
        for (int q = 0; q < JP / 4; ++q) {
            float4 wv = *reinterpret_cast<const float4*>(&Wl[i * 64 + lane * JP + q * 4]);
            m[q].x += p * wv.x; m[q].y += p * wv.y;
            m[q].z += p * wv.z; m[q].w += p * wv.w;
        }
    }

    if (valid) {
        size_t o = (size_t)node * 64 + lane * JP;
#pragma unroll
        for (int q = 0; q < JP / 4; ++q) {
            float4 cv = *reinterpret_cast<const float4*>(&acc[o + q * 4]);
            float4 r = {cv.x + m[q].x, cv.y + m[q].y, cv.z + m[q].z, cv.w + m[q].w};
            if (MODE == 0) {
                *reinterpret_cast<float4*>(&acc[o + q * 4]) = r;
            } else {
                float4 bv = *reinterpret_cast<const float4*>(&bias[lane * JP + q * 4]);
                r.x = fmaxf(r.x + bv.x, 0.f);
                r.y = fmaxf(r.y + bv.y, 0.f);
                r.z = fmaxf(r.z + bv.z, 0.f);
                r.w = fmaxf(r.w + bv.w, 0.f);
                if (MODE == 1) store_half4(hdst + o + q * 4, r);   // FIX: was hdst + o (q=1 quad clobbered q=0)
                else           *reinterpret_cast<float4*>(&fdst[o + q * 4]) = r;
            }
        }
    }
}

// ---------------- host ----------------

extern "C" void kernel_launch(void* const* d_in, const int* in_sizes, int n_in,
                              void* d_out, int out_size, void* d_ws, size_t ws_size,
                              hipStream_t stream) {
    const float* x  = (const float*)d_in[0];
    const int*   ei = (const int*)d_in[1];
    const float* ew = (const float*)d_in[2];
    const float* W0 = (const float*)d_in[3];
    const float* b0 = (const float*)d_in[4];
    const float* Ws = (const float*)d_in[5];
    const float* bs = (const float*)d_in[6];
    float* out = (float*)d_out;

    const int* row = ei;
    const int* col = ei + NE;

    char* wsp = (char*)d_ws;
    auto alloc = [&](size_t bytes) -> char* {
        char* p = wsp;
        wsp += (bytes + 255) & ~(size_t)255;
        return p;
    };
    float*    dinv    = (float*)alloc(NN * 4);
    unsigned* cnt     = (unsigned*)alloc(NN * 4);
    unsigned* cursor  = (unsigned*)alloc(NN * 4);
    unsigned* offsets = (unsigned*)alloc(NN * 4);
    unsigned* bsum    = (unsigned*)alloc(256 * 4);
    unsigned* bbase   = (unsigned*)alloc(256 * 4);
    int2*     ent     = (int2*)alloc((size_t)NE * 8);
    half_t*   B0      = (half_t*)alloc((size_t)NN * 64 * 2);  // h (layer input)
    half_t*   B1      = (half_t*)alloc((size_t)NN * 64 * 2);  // hop ping
    half_t*   B2      = (half_t*)alloc((size_t)NN * 64 * 2);  // hop pong

    hipMemsetAsync(cnt, 0, NN * 4, stream);
    hipMemsetAsync(cursor, 0, NN * 4, stream);

    const int EB = (NE + 255) / 256;         // 6250
    const int NB = (NN + 1023) / 1024;       // 98
    cnt_hist<<<EB, 256, 0, stream>>>(col, cnt, NE);
    scan_phase1<<<NB, 256, 0, stream>>>(cnt, bsum, NN);
    scan_phase2<<<1, 128, 0, stream>>>(bsum, bbase, NB);
    scan_phase3<<<NB, 256, 0, stream>>>(cnt, bbase, offsets, NN);
    csr_build<<<EB, 256, 0, stream>>>(row, col, ew, offsets, cursor, ent, NE);
    deg_dinv<<<(NN + 255) / 256, 256, 0, stream>>>(ent, offsets, cnt, dinv, NN);
    norm_scale<<<EB, 256, 0, stream>>>(ent, dinv, NE);

    const int MMB = (NN + 63) / 64;          // 1563
    const int SB32 = (NN + 31) / 32;         // 3125 (32 nodes/block)
    const int SB64 = (NN + 15) / 16;         // 6250 (16 nodes/block)

    // ---- layer 0 (gather dim 32) ----
    matmul_kernel<32, float><<<MMB, 256, 0, stream>>>(x, W0, out, NN);
    spmm_mm_kernel<32, float, 0><<<SB32, 256, 0, stream>>>(
        x, B1, ent, offsets, cnt, dinv, W0 + 2048, out, nullptr, nullptr, nullptr, NN);
    spmm_mm_kernel<32, half_t, 0><<<SB32, 256, 0, stream>>>(
        B1, B2, ent, offsets, cnt, dinv, W0 + 4096, out, nullptr, nullptr, nullptr, NN);
    spmm_mm_kernel<32, half_t, 1><<<SB32, 256, 0, stream>>>(
        B2, nullptr, ent, offsets, cnt, dinv, W0 + 6144, out, b0, B0, nullptr, NN);

    // ---- layers 1..4 (gather dim 64) ----
    for (int l = 0; l < 4; ++l) {
        const float* Wl = Ws + (size_t)l * 4 * 64 * 64;
        const float* bl = bs + (size_t)l * 64;
        matmul_kernel<64, half_t><<<MMB, 256, 0, stream>>>(B0, Wl, out, NN);
        spmm_mm_kernel<64, half_t, 0><<<SB64, 256, 0, stream>>>(
            B0, B1, ent, offsets, cnt, dinv, Wl + 4096, out, nullptr, nullptr, nullptr, NN);
        spmm_mm_kernel<64, half_t, 0><<<SB64, 256, 0, stream>>>(
            B1, B2, ent, offsets, cnt, dinv, Wl + 8192, out, nullptr, nullptr, nullptr, NN);
        if (l < 3)
            spmm_mm_kernel<64, half_t, 1><<<SB64, 256, 0, stream>>>(
                B2, nullptr, ent, offsets, cnt, dinv, Wl + 12288, out, bl, B0, nullptr, NN);
        else
            spmm_mm_kernel<64, half_t, 2><<<SB64, 256, 0, stream>>>(
                B2, nullptr, ent, offsets, cnt, dinv, Wl + 12288, out, bl, nullptr, out, NN);
    }
}